// Round 3
// baseline (1535.776 us; speedup 1.0000x reference)
//
#include <hip/hip_runtime.h>

#define S_LEN 2048
#define NH 32
#define NKV 8
#define HDIM 128

using half8  = __attribute__((ext_vector_type(8))) _Float16;
using half4  = __attribute__((ext_vector_type(4))) _Float16;
using half2v = __attribute__((ext_vector_type(2))) _Float16;
using f32x4  = __attribute__((ext_vector_type(4))) float;

__device__ __forceinline__ void gll16(const void* g, void* l) {
  __builtin_amdgcn_global_load_lds(
      (const __attribute__((address_space(1))) void*)g,
      (__attribute__((address_space(3))) void*)l, 16, 0, 0);
}

// ---------------- cast f32 -> f16 (4 elems/thread) ----------------
__global__ __launch_bounds__(256) void cast_f16_kernel(const float* __restrict__ in,
                                                       _Float16* __restrict__ out, int n4) {
  int i = blockIdx.x * 256 + threadIdx.x;
  if (i >= n4) return;
  float4 v = reinterpret_cast<const float4*>(in)[i];
  half4 o = { (_Float16)v.x, (_Float16)v.y, (_Float16)v.z, (_Float16)v.w };
  reinterpret_cast<half4*>(out)[i] = o;
}

// ---------------- RoPE in-place on f16, one (pair) per thread ----------------
// t layout: [B, S, nheads, HDIM]; pair i covers elements 2i, 2i+1.
// out[j] = t0*fc[s][m][j][0] + t1*fc[s][m][j][1], then * scale.
__global__ __launch_bounds__(256) void rope_kernel(_Float16* __restrict__ t,
                                                   const float* __restrict__ fc,
                                                   int nheads, float scale, int npairs) {
  int i = blockIdx.x * 256 + threadIdx.x;
  if (i >= npairs) return;
  int m = i & 63;                      // pair index within head dim
  int s = (i / (nheads * 64)) % S_LEN; // sequence position
  half2v tv = reinterpret_cast<half2v*>(t)[i];
  float4 f = reinterpret_cast<const float4*>(fc)[s * 64 + m]; // [j=0,m0],[j=0,m1],[j=1,m0],[j=1,m1]
  float t0 = (float)tv[0], t1 = (float)tv[1];
  half2v o = { (_Float16)((t0 * f.x + t1 * f.y) * scale),
               (_Float16)((t0 * f.z + t1 * f.w) * scale) };
  reinterpret_cast<half2v*>(t)[i] = o;
}

// ---------------- GEMM: C[M,N] = A[M,K] * B[N,K]^T, f16 in, f16/f32 out ------
// m97 structure: 128x128 tile, BK=32, 4 waves (2x2), 4x4 16x16 frags per wave.
template <int F32OUT>
__global__ __launch_bounds__(256) void gemm_bt_kernel(const _Float16* __restrict__ A,
                                                      const _Float16* __restrict__ B,
                                                      void* __restrict__ Cv,
                                                      int M, int N, int K) {
  __shared__ _Float16 As[128 * 32];
  __shared__ _Float16 Bs[128 * 32];
  const int tid = threadIdx.x;
  const int wv = tid >> 6, ln = tid & 63;
  const int m0 = blockIdx.y * 128, n0 = blockIdx.x * 128;
  const int wm = wv >> 1, wn = wv & 1;
  const int g = ln >> 4, c = ln & 15;
  const int srow = ln >> 2, scol = (ln & 3) * 8; // staging: lane -> row/col within 16-row chunk
  f32x4 acc[4][4] = {};

  for (int k0 = 0; k0 < K; k0 += 32) {
    // stage A,B tiles: 8 chunks of 1KB each (16 rows x 64B), wave j covers chunk j, j+4
    for (int j = wv; j < 8; j += 4) {
      gll16(A + (size_t)(m0 + j * 16 + srow) * K + k0 + scol, (char*)As + j * 1024);
      gll16(B + (size_t)(n0 + j * 16 + srow) * K + k0 + scol, (char*)Bs + j * 1024);
    }
    __syncthreads();
    half8 af[4], bfr[4];
#pragma unroll
    for (int m = 0; m < 4; ++m)
      af[m] = *reinterpret_cast<const half8*>(&As[(wm * 64 + m * 16 + c) * 32 + g * 8]);
#pragma unroll
    for (int n = 0; n < 4; ++n)
      bfr[n] = *reinterpret_cast<const half8*>(&Bs[(wn * 64 + n * 16 + c) * 32 + g * 8]);
#pragma unroll
    for (int m = 0; m < 4; ++m)
#pragma unroll
      for (int n = 0; n < 4; ++n)
        acc[m][n] = __builtin_amdgcn_mfma_f32_16x16x32_f16(af[m], bfr[n], acc[m][n], 0, 0, 0);
    __syncthreads();
  }
  // epilogue: C/D layout col=lane&15, row=(lane>>4)*4+reg
#pragma unroll
  for (int m = 0; m < 4; ++m)
#pragma unroll
    for (int n = 0; n < 4; ++n)
#pragma unroll
      for (int r = 0; r < 4; ++r) {
        int row = m0 + wm * 64 + m * 16 + g * 4 + r;
        int col = n0 + wn * 64 + n * 16 + c;
        if (F32OUT)
          reinterpret_cast<float*>(Cv)[(size_t)row * N + col] = acc[m][n][r];
        else
          reinterpret_cast<_Float16*>(Cv)[(size_t)row * N + col] = (_Float16)acc[m][n][r];
      }
}

// ---------------- Flash attention, causal, GQA ----------------
// Q:[B,S,NH,HD] f16 (pre-scaled by 1/sqrt(HD) in rope), K,V:[B,S,NKV,HD] f16.
// Block: 64 q-rows (4 waves x 16), KVBLK=64.
__global__ __launch_bounds__(256) void attn_kernel(const _Float16* __restrict__ Q,
                                                   const _Float16* __restrict__ K,
                                                   const _Float16* __restrict__ V,
                                                   _Float16* __restrict__ O) {
  const int b = blockIdx.z, h = blockIdx.y, qt = blockIdx.x;
  const int kvh = h >> 2; // G=4
  const int tid = threadIdx.x, w = tid >> 6, ln = tid & 63;
  const int g = ln >> 4, c = ln & 15;
  const int q0 = qt * 64, q0w = q0 + w * 16;

  __shared__ _Float16 Ks[64 * 128];    // XOR-swizzled rows
  __shared__ _Float16 Vt[128 * 72];    // transposed [d][key], padded stride 72
  __shared__ _Float16 Ps[4][16 * 72];  // per-wave P tile [16 q][64 key], padded

  // Q fragments: A-operand, lane holds Q[q0w + (ln&15)][g*8+j + 32*cc]
  half8 aq[4];
  {
    const _Float16* qp = Q + ((size_t)(b * S_LEN + q0w + c) * NH + h) * HDIM + g * 8;
#pragma unroll
    for (int cc = 0; cc < 4; ++cc) aq[cc] = *reinterpret_cast<const half8*>(qp + cc * 32);
  }

  float mrow[4], lrow[4];
  f32x4 oacc[8] = {};
#pragma unroll
  for (int r = 0; r < 4; ++r) { mrow[r] = -1e30f; lrow[r] = 0.f; }

  const int srow = tid >> 4, scol = (tid & 15) * 8;
  const int ntile = qt + 1;
  for (int t = 0; t < ntile; ++t) {
    const int kv0 = t * 64;
    // ---- stage K (swizzled rows) and V^T ----
#pragma unroll
    for (int p = 0; p < 4; ++p) {
      int row = srow + p * 16;
      size_t gbase = ((size_t)(b * S_LEN + kv0 + row) * NKV + kvh) * HDIM + scol;
      half8 kvv = *reinterpret_cast<const half8*>(K + gbase);
      int lin = row * 256 + scol * 2;
      *reinterpret_cast<half8*>((char*)Ks + (lin ^ ((row & 7) << 4))) = kvv;
      half8 vv = *reinterpret_cast<const half8*>(V + gbase);
#pragma unroll
      for (int j = 0; j < 8; ++j) Vt[(scol + j) * 72 + row] = vv[j];
    }
    __syncthreads();

    // ---- QK^T: S[16q x 64k] in 4 frags ----
    f32x4 sf[4];
#pragma unroll
    for (int kt = 0; kt < 4; ++kt) {
      f32x4 a = {};
      int row = kt * 16 + c;
#pragma unroll
      for (int cc = 0; cc < 4; ++cc) {
        int lin = row * 256 + cc * 64 + g * 16;
        half8 kf = *reinterpret_cast<const half8*>((const char*)Ks + (lin ^ ((row & 7) << 4)));
        a = __builtin_amdgcn_mfma_f32_16x16x32_f16(aq[cc], kf, a, 0, 0, 0);
      }
      sf[kt] = a;
    }
    // causal mask (diagonal tile only)
    if (t == qt) {
#pragma unroll
      for (int kt = 0; kt < 4; ++kt)
#pragma unroll
        for (int r = 0; r < 4; ++r)
          if (kv0 + kt * 16 + c > q0w + g * 4 + r) sf[kt][r] = -1e9f;
    }

    // ---- online softmax (row = g*4+r, reduce across 16 lanes of same group) ----
    float alpha[4], tsum[4];
#pragma unroll
    for (int r = 0; r < 4; ++r) {
      float mx = fmaxf(fmaxf(sf[0][r], sf[1][r]), fmaxf(sf[2][r], sf[3][r]));
#pragma unroll
      for (int msk = 1; msk < 16; msk <<= 1) mx = fmaxf(mx, __shfl_xor(mx, msk));
      float mnew = fmaxf(mrow[r], mx);
      alpha[r] = __expf(mrow[r] - mnew);
      mrow[r] = mnew;
      tsum[r] = 0.f;
    }
#pragma unroll
    for (int kt = 0; kt < 4; ++kt)
#pragma unroll
      for (int r = 0; r < 4; ++r) {
        float p = __expf(sf[kt][r] - mrow[r]);
        tsum[r] += p;
        Ps[w][(g * 4 + r) * 72 + kt * 16 + c] = (_Float16)p;
      }
#pragma unroll
    for (int r = 0; r < 4; ++r) {
      float ts = tsum[r];
#pragma unroll
      for (int msk = 1; msk < 16; msk <<= 1) ts += __shfl_xor(ts, msk);
      lrow[r] = lrow[r] * alpha[r] + ts;
    }
#pragma unroll
    for (int n = 0; n < 8; ++n)
#pragma unroll
      for (int r = 0; r < 4; ++r) oacc[n][r] *= alpha[r];

    // ---- PV: O += P[16x64] * V[64x128] ----
#pragma unroll
    for (int kk = 0; kk < 2; ++kk) {
      half8 pa = *reinterpret_cast<const half8*>(&Ps[w][c * 72 + kk * 32 + g * 8]);
#pragma unroll
      for (int n = 0; n < 8; ++n) {
        half8 vf = *reinterpret_cast<const half8*>(&Vt[(n * 16 + c) * 72 + kk * 32 + g * 8]);
        oacc[n] = __builtin_amdgcn_mfma_f32_16x16x32_f16(pa, vf, oacc[n], 0, 0, 0);
      }
    }
    __syncthreads();
  }

  float inv[4];
#pragma unroll
  for (int r = 0; r < 4; ++r) inv[r] = 1.0f / lrow[r];
#pragma unroll
  for (int n = 0; n < 8; ++n)
#pragma unroll
    for (int r = 0; r < 4; ++r)
      O[((size_t)(b * S_LEN + q0w + g * 4 + r) * NH + h) * HDIM + n * 16 + c] =
          (_Float16)(oacc[n][r] * inv[r]);
}

// ---------------- launcher ----------------
extern "C" void kernel_launch(void* const* d_in, const int* in_sizes, int n_in,
                              void* d_out, int out_size, void* d_ws, size_t ws_size,
                              hipStream_t stream) {
  const float* x  = (const float*)d_in[0];
  const float* fc = (const float*)d_in[1];
  const float* wq = (const float*)d_in[2];
  const float* wk = (const float*)d_in[3];
  const float* wv = (const float*)d_in[4];
  const float* wo = (const float*)d_in[5];
  float* out = (float*)d_out;
  char* ws = (char*)d_ws;

  const int NX  = 16777216; // 2*2048*4096  (x, also wq/wo count)
  const int NWK = 4194304;  // 1024*4096

  // workspace layout with liveness-based reuse (total 80 MB):
  _Float16* xb  = (_Float16*)(ws);              // [0, 32MB)   x_f16; dead after V gemm
  _Float16* wqb = (_Float16*)(ws + 33554432);   // [32, 64MB)  wq_f16; dead after Q gemm
  _Float16* wkb = (_Float16*)(ws + 67108864);   // [64, 72MB)  wk_f16; dead after K gemm
  _Float16* wvb = (_Float16*)(ws + 75497472);   // [72, 80MB)  wv_f16; dead after V gemm
  _Float16* vb  = (_Float16*)(ws + 67108864);   // reuse wkb slot: V (b,s,kv,hd)
  _Float16* ao  = (_Float16*)(ws + 33554432);   // reuse wqb slot: attn out (b,s,h,hd)
  _Float16* wob = (_Float16*)(ws);              // reuse xb slot: wo_f16
  // d_out (64MB f32) doubles as scratch for Q and K until the final GEMM:
  _Float16* qb  = (_Float16*)d_out;                      // 32MB
  _Float16* kb  = (_Float16*)((char*)d_out + 33554432);  // 8MB

  // 1. casts (x, wq, wk, wv)
  cast_f16_kernel<<<dim3(NX / 4 / 256), 256, 0, stream>>>(x, xb, NX / 4);
  cast_f16_kernel<<<dim3(NX / 4 / 256), 256, 0, stream>>>(wq, wqb, NX / 4);
  cast_f16_kernel<<<dim3(NWK / 4 / 256), 256, 0, stream>>>(wk, wkb, NWK / 4);
  cast_f16_kernel<<<dim3(NWK / 4 / 256), 256, 0, stream>>>(wv, wvb, NWK / 4);

  // 2. QKV projections
  gemm_bt_kernel<0><<<dim3(32, 32), 256, 0, stream>>>(xb, wqb, qb, 4096, 4096, 4096);
  gemm_bt_kernel<0><<<dim3(8, 32), 256, 0, stream>>>(xb, wkb, kb, 4096, 1024, 4096);
  gemm_bt_kernel<0><<<dim3(8, 32), 256, 0, stream>>>(xb, wvb, vb, 4096, 1024, 4096);

  // 3. cast wo into xb slot (xb now dead)
  cast_f16_kernel<<<dim3(NX / 4 / 256), 256, 0, stream>>>(wo, wob, NX / 4);

  // 4. RoPE (q pre-scaled by 1/sqrt(128))
  const float scale = 0.08838834764831845f;
  rope_kernel<<<dim3(8388608 / 256), 256, 0, stream>>>(qb, fc, NH, scale, 8388608);
  rope_kernel<<<dim3(2097152 / 256), 256, 0, stream>>>(kb, fc, NKV, 1.0f, 2097152);

  // 5. attention
  attn_kernel<<<dim3(32, 32, 2), 256, 0, stream>>>(qb, kb, vb, ao);

  // 6. output projection -> f32 d_out
  gemm_bt_kernel<1><<<dim3(32, 32), 256, 0, stream>>>(ao, wob, out, 4096, 4096, 4096);
}

// Round 7
// 1160.866 us; speedup vs baseline: 1.3230x; 1.3230x over previous
//
#include <hip/hip_runtime.h>

#define S_LEN 2048
#define NH 32
#define NKV 8
#define HDIM 128

using half8  = __attribute__((ext_vector_type(8))) _Float16;
using half4  = __attribute__((ext_vector_type(4))) _Float16;
using half2v = __attribute__((ext_vector_type(2))) _Float16;
using f32x4  = __attribute__((ext_vector_type(4))) float;

__device__ __forceinline__ void gll16(const void* g, void* l) {
  __builtin_amdgcn_global_load_lds(
      (const __attribute__((address_space(1))) void*)g,
      (__attribute__((address_space(3))) void*)l, 16, 0, 0);
}

// ---------------- cast f32 -> f16 (4 elems/thread) ----------------
__global__ __launch_bounds__(256) void cast_f16_kernel(const float* __restrict__ in,
                                                       _Float16* __restrict__ out, int n4) {
  int i = blockIdx.x * 256 + threadIdx.x;
  if (i >= n4) return;
  float4 v = reinterpret_cast<const float4*>(in)[i];
  half4 o = { (_Float16)v.x, (_Float16)v.y, (_Float16)v.z, (_Float16)v.w };
  reinterpret_cast<half4*>(out)[i] = o;
}

// ---------------- RoPE in-place on f16 ----------------
__global__ __launch_bounds__(256) void rope_kernel(_Float16* __restrict__ t,
                                                   const float* __restrict__ fc,
                                                   int nheads, float scale, int npairs) {
  int i = blockIdx.x * 256 + threadIdx.x;
  if (i >= npairs) return;
  int m = i & 63;
  int s = (i / (nheads * 64)) % S_LEN;
  half2v tv = reinterpret_cast<half2v*>(t)[i];
  float4 f = reinterpret_cast<const float4*>(fc)[s * 64 + m];
  float t0 = (float)tv[0], t1 = (float)tv[1];
  half2v o = { (_Float16)((t0 * f.x + t1 * f.y) * scale),
               (_Float16)((t0 * f.z + t1 * f.w) * scale) };
  reinterpret_cast<half2v*>(t)[i] = o;
}

// ---------------- GEMM: C[M,N] = A[M,K] * B[N,K]^T (m97 structure) ----------
template <int F32OUT>
__global__ __launch_bounds__(256) void gemm_bt_kernel(const _Float16* __restrict__ A,
                                                      const _Float16* __restrict__ B,
                                                      void* __restrict__ Cv,
                                                      int M, int N, int K) {
  __shared__ _Float16 As[128 * 32];
  __shared__ _Float16 Bs[128 * 32];
  const int tid = threadIdx.x;
  const int wv = tid >> 6, ln = tid & 63;
  const int m0 = blockIdx.y * 128, n0 = blockIdx.x * 128;
  const int wm = wv >> 1, wn = wv & 1;
  const int g = ln >> 4, c = ln & 15;
  const int srow = ln >> 2, scol = (ln & 3) * 8;
  f32x4 acc[4][4] = {};

  for (int k0 = 0; k0 < K; k0 += 32) {
    for (int j = wv; j < 8; j += 4) {
      gll16(A + (size_t)(m0 + j * 16 + srow) * K + k0 + scol, (char*)As + j * 1024);
      gll16(B + (size_t)(n0 + j * 16 + srow) * K + k0 + scol, (char*)Bs + j * 1024);
    }
    __syncthreads();
    half8 af[4], bfr[4];
#pragma unroll
    for (int m = 0; m < 4; ++m)
      af[m] = *reinterpret_cast<const half8*>(&As[(wm * 64 + m * 16 + c) * 32 + g * 8]);
#pragma unroll
    for (int n = 0; n < 4; ++n)
      bfr[n] = *reinterpret_cast<const half8*>(&Bs[(wn * 64 + n * 16 + c) * 32 + g * 8]);
#pragma unroll
    for (int m = 0; m < 4; ++m)
#pragma unroll
      for (int n = 0; n < 4; ++n)
        acc[m][n] = __builtin_amdgcn_mfma_f32_16x16x32_f16(af[m], bfr[n], acc[m][n], 0, 0, 0);
    __syncthreads();
  }
#pragma unroll
  for (int m = 0; m < 4; ++m)
#pragma unroll
    for (int n = 0; n < 4; ++n)
#pragma unroll
      for (int r = 0; r < 4; ++r) {
        int row = m0 + wm * 64 + m * 16 + g * 4 + r;
        int col = n0 + wn * 64 + n * 16 + c;
        if (F32OUT)
          reinterpret_cast<float*>(Cv)[(size_t)row * N + col] = acc[m][n][r];
        else
          reinterpret_cast<_Float16*>(Cv)[(size_t)row * N + col] = (_Float16)acc[m][n][r];
      }
}

// ---------------- V transpose: V[b][s][kvh][d] -> Vt[b*8+kvh][d][s] ---------
// LDS tile [64 k][128 d], skewed: byte addr = 256*k + (2*d ^ 32*((k>>3)&7)).
// Staging writes conflict-free (lane-spread d); gather reads 2-way (free).
__global__ __launch_bounds__(256) void vt_kernel(const _Float16* __restrict__ V,
                                                 _Float16* __restrict__ Vt) {
  const int kt = blockIdx.x;  // 32 key tiles of 64
  const int bh = blockIdx.y;  // 16 (b, kvh)
  const int b = bh >> 3, kvh = bh & 7;
  __shared__ char T[16384];
  const int tid = threadIdx.x;
  const int sk = tid >> 4, sd = (tid & 15) * 8;
#pragma unroll
  for (int p = 0; p < 4; ++p) {
    int k = sk + 16 * p;
    half8 v = *reinterpret_cast<const half8*>(
        V + ((size_t)(b * S_LEN + kt * 64 + k) * NKV + kvh) * HDIM + sd);
    *reinterpret_cast<half8*>(T + 256 * k + ((2 * sd) ^ (32 * ((k >> 3) & 7)))) = v;
  }
  __syncthreads();
  const int k0 = 8 * ((tid >> 4) & 7);
  const int dbase = (tid & 15) + 16 * (tid >> 7);
  const int skew = 32 * ((k0 >> 3) & 7);
#pragma unroll
  for (int dp = 0; dp < 4; ++dp) {
    int d = dbase + 32 * dp;
    half8 o;
#pragma unroll
    for (int j = 0; j < 8; ++j)
      o[j] = *reinterpret_cast<const _Float16*>(T + 256 * (k0 + j) + ((2 * d) ^ skew));
    *reinterpret_cast<half8*>(Vt + ((size_t)bh * HDIM + d) * S_LEN + kt * 64 + k0) = o;
  }
}

// ---------------- Flash attention, causal, GQA ----------------
// Q:[B,S,NH,HD] f16 (pre-scaled), K:[B,S,NKV,HD] f16, Vt:[b*8+kvh][d][s] f16.
// Round-3 verified structure; V now staged row-major-by-d with the same
// 16B XOR swizzle as K (T2). T14 prefetch of next tile into registers.
__global__ __launch_bounds__(256) void attn_kernel(const _Float16* __restrict__ Q,
                                                   const _Float16* __restrict__ K,
                                                   const _Float16* __restrict__ Vt,
                                                   _Float16* __restrict__ O) {
  const int b = blockIdx.z, h = blockIdx.y, qt = 31 - blockIdx.x;  // big blocks first
  const int kvh = h >> 2, bh = b * NKV + kvh;
  const int tid = threadIdx.x, w = tid >> 6, ln = tid & 63;
  const int g = ln >> 4, c = ln & 15;
  const int q0w = qt * 64 + w * 16;

  __shared__ _Float16 Ks[64 * 128];   // [key][d], byte lin ^ ((key&7)<<4)
  __shared__ _Float16 Vl[128 * 64];   // [d][key], byte lin ^ ((d&7)<<4)
  __shared__ _Float16 Ps[4][16 * 72]; // per-wave P [q][key], pad stride 72

  half8 aq[4];
  {
    const _Float16* qp = Q + ((size_t)(b * S_LEN + q0w + c) * NH + h) * HDIM + g * 8;
#pragma unroll
    for (int cc = 0; cc < 4; ++cc) aq[cc] = *reinterpret_cast<const half8*>(qp + cc * 32);
  }

  float mrow[4], lrow[4];
  f32x4 oacc[8] = {};
#pragma unroll
  for (int r = 0; r < 4; ++r) { mrow[r] = -1e30f; lrow[r] = 0.f; }

  const int srow = tid >> 4, scol = (tid & 15) * 8;  // K staging
  const int dv = tid >> 1, kv0 = (tid & 1) * 32;     // V staging
  const _Float16* Vbase = Vt + ((size_t)bh * HDIM + dv) * S_LEN;

  half8 kreg[4], vreg[4];
  auto load_tile = [&](int t) {
#pragma unroll
    for (int p = 0; p < 4; ++p) {
      kreg[p] = *reinterpret_cast<const half8*>(
          K + ((size_t)(b * S_LEN + t * 64 + srow + 16 * p) * NKV + kvh) * HDIM + scol);
      vreg[p] = *reinterpret_cast<const half8*>(Vbase + t * 64 + kv0 + 8 * p);
    }
  };
  load_tile(0);

  const int ntile = qt + 1;
  for (int t = 0; t < ntile; ++t) {
    __syncthreads();  // previous tile's LDS reads complete
#pragma unroll
    for (int p = 0; p < 4; ++p) {
      int key = srow + 16 * p;
      int klin = key * 256 + scol * 2;
      *reinterpret_cast<half8*>((char*)Ks + (klin ^ ((key & 7) << 4))) = kreg[p];
      int vlin = dv * 128 + (kv0 + 8 * p) * 2;
      *reinterpret_cast<half8*>((char*)Vl + (vlin ^ ((dv & 7) << 4))) = vreg[p];
    }
    __syncthreads();  // tile t staged
    if (t + 1 < ntile) load_tile(t + 1);  // T14: overlaps compute below

    // ---- QK^T: sf[kt][r] = S[q=g*4+r][key=kt*16+c] ----
    f32x4 sf[4];
#pragma unroll
    for (int kt2 = 0; kt2 < 4; ++kt2) {
      f32x4 a = {};
      int row = kt2 * 16 + c;
#pragma unroll
      for (int cc = 0; cc < 4; ++cc) {
        int lin = row * 256 + cc * 64 + g * 16;
        half8 kf = *reinterpret_cast<const half8*>((const char*)Ks + (lin ^ ((row & 7) << 4)));
        a = __builtin_amdgcn_mfma_f32_16x16x32_f16(aq[cc], kf, a, 0, 0, 0);
      }
      sf[kt2] = a;
    }
    if (t == qt) {  // causal mask on diagonal tile
#pragma unroll
      for (int kt2 = 0; kt2 < 4; ++kt2)
#pragma unroll
        for (int r = 0; r < 4; ++r)
          if (t * 64 + kt2 * 16 + c > q0w + g * 4 + r) sf[kt2][r] = -1e9f;
    }

    // ---- online softmax (reduce across 16 lanes of each group) ----
    float alpha[4], tsum[4];
#pragma unroll
    for (int r = 0; r < 4; ++r) {
      float mx = fmaxf(fmaxf(sf[0][r], sf[1][r]), fmaxf(sf[2][r], sf[3][r]));
#pragma unroll
      for (int msk = 1; msk < 16; msk <<= 1) mx = fmaxf(mx, __shfl_xor(mx, msk));
      float mnew = fmaxf(mrow[r], mx);
      alpha[r] = __expf(mrow[r] - mnew);
      mrow[r] = mnew;
      tsum[r] = 0.f;
    }
#pragma unroll
    for (int kt2 = 0; kt2 < 4; ++kt2)
#pragma unroll
      for (int r = 0; r < 4; ++r) {
        float p = __expf(sf[kt2][r] - mrow[r]);
        tsum[r] += p;
        Ps[w][(g * 4 + r) * 72 + kt2 * 16 + c] = (_Float16)p;
      }
#pragma unroll
    for (int r = 0; r < 4; ++r) {
      float ts = tsum[r];
#pragma unroll
      for (int msk = 1; msk < 16; msk <<= 1) ts += __shfl_xor(ts, msk);
      lrow[r] = lrow[r] * alpha[r] + ts;
    }
#pragma unroll
    for (int n = 0; n < 8; ++n)
#pragma unroll
      for (int r = 0; r < 4; ++r) oacc[n][r] *= alpha[r];

    // ---- PV: O += P[16x64] * V[64x128]; B-frag = swizzled Vl row d=16n+c ----
#pragma unroll
    for (int kk = 0; kk < 2; ++kk) {
      half8 pa = *reinterpret_cast<const half8*>(&Ps[w][c * 72 + kk * 32 + g * 8]);
#pragma unroll
      for (int n = 0; n < 8; ++n) {
        int d = n * 16 + c;
        int vlin = d * 128 + (kk * 32 + g * 8) * 2;
        half8 vf = *reinterpret_cast<const half8*>((const char*)Vl + (vlin ^ ((d & 7) << 4)));
        oacc[n] = __builtin_amdgcn_mfma_f32_16x16x32_f16(pa, vf, oacc[n], 0, 0, 0);
      }
    }
  }

  float inv[4];
#pragma unroll
  for (int r = 0; r < 4; ++r) inv[r] = 1.0f / lrow[r];
#pragma unroll
  for (int n = 0; n < 8; ++n)
#pragma unroll
    for (int r = 0; r < 4; ++r)
      O[((size_t)(b * S_LEN + q0w + g * 4 + r) * NH + h) * HDIM + n * 16 + c] =
          (_Float16)(oacc[n][r] * inv[r]);
}

// ---------------- launcher ----------------
extern "C" void kernel_launch(void* const* d_in, const int* in_sizes, int n_in,
                              void* d_out, int out_size, void* d_ws, size_t ws_size,
                              hipStream_t stream) {
  const float* x  = (const float*)d_in[0];
  const float* fc = (const float*)d_in[1];
  const float* wq = (const float*)d_in[2];
  const float* wk = (const float*)d_in[3];
  const float* wv = (const float*)d_in[4];
  const float* wo = (const float*)d_in[5];
  float* out = (float*)d_out;
  char* ws = (char*)d_ws;

  const int NX  = 16777216; // 2*2048*4096
  const int NWK = 4194304;  // 1024*4096

  // workspace (80 MB, liveness-reused):
  _Float16* xb  = (_Float16*)(ws);              // [0,32M)  x_f16
  _Float16* wqb = (_Float16*)(ws + 33554432);   // [32,64M) wq_f16
  _Float16* wkb = (_Float16*)(ws + 67108864);   // [64,72M) wk_f16
  _Float16* wvb = (_Float16*)(ws + 75497472);   // [72,80M) wv_f16; dead after V gemm
  _Float16* vb  = (_Float16*)(ws + 67108864);   // reuse wkb: V (b,s,kv,hd)
  _Float16* vtg = (_Float16*)(ws + 75497472);   // reuse wvb: Vt (bh,d,s) 8MB
  _Float16* ao  = (_Float16*)(ws + 33554432);   // reuse wqb: attn out
  _Float16* wob = (_Float16*)(ws);              // reuse xb: wo_f16
  _Float16* qb  = (_Float16*)d_out;                      // 32MB scratch in d_out
  _Float16* kb  = (_Float16*)((char*)d_out + 33554432);  // 8MB

  cast_f16_kernel<<<dim3(NX / 4 / 256), 256, 0, stream>>>(x, xb, NX / 4);
  cast_f16_kernel<<<dim3(NX / 4 / 256), 256, 0, stream>>>(wq, wqb, NX / 4);
  cast_f16_kernel<<<dim3(NWK / 4 / 256), 256, 0, stream>>>(wk, wkb, NWK / 4);
  cast_f16_kernel<<<dim3(NWK / 4 / 256), 256, 0, stream>>>(wv, wvb, NWK / 4);

  gemm_bt_kernel<0><<<dim3(32, 32), 256, 0, stream>>>(xb, wqb, qb, 4096, 4096, 4096);
  gemm_bt_kernel<0><<<dim3(8, 32), 256, 0, stream>>>(xb, wkb, kb, 4096, 1024, 4096);
  gemm_bt_kernel<0><<<dim3(8, 32), 256, 0, stream>>>(xb, wvb, vb, 4096, 1024, 4096);

  vt_kernel<<<dim3(32, 16), 256, 0, stream>>>(vb, vtg);  // V -> Vt (wvb now dead)

  cast_f16_kernel<<<dim3(NX / 4 / 256), 256, 0, stream>>>(wo, wob, NX / 4);

  const float scale = 0.08838834764831845f;
  rope_kernel<<<dim3(8388608 / 256), 256, 0, stream>>>(qb, fc, NH, scale, 8388608);
  rope_kernel<<<dim3(2097152 / 256), 256, 0, stream>>>(kb, fc, NKV, 1.0f, 2097152);

  attn_kernel<<<dim3(32, 32, 2), 256, 0, stream>>>(qb, kb, vtg, ao);

  gemm_bt_kernel<1><<<dim3(32, 32), 256, 0, stream>>>(ao, wob, out, 4096, 4096, 4096);
}